// Round 15
// baseline (250.679 us; speedup 1.0000x reference)
//
#include <hip/hip_runtime.h>

// 3-layer GCN + mean pool. MFMA GEMM / fp32 accumulate / uint8 interchange.
// R27: wave-private staging -- delete the block convoy.
// R26 landed 44us/layer (uint8, 8 blocks/CU). Accounting: 45 cy/edge/CU
// with ~2-4cy issue work and 1.75TB/s line stream -> neither issue- nor
// BW-bound; the residual is the block-wide chunk convoy (colread-bar-
// stage-drain-bar-reduce-bar x chunks). This round each WAVE owns its 4
// nodes end-to-end: private col/scale read (wave-local LDS, no barrier),
// private gload_lds stg region, wave-local vmcnt drain, reduce, deposit,
// then ONE block barrier before MFMA. Barriers/block: ~5 -> 2; stalls
// hidden by 27 other waves (pure TLP) instead of block rendezvous.
// Capacity 32 edges/wave/round (P(Poisson(12)>32)~1e-8; wave-local
// multi-round fallback). LDS ~21.4KB -> 7 blocks/CU.

#define DIN 30
#define HD  128

typedef __attribute__((ext_vector_type(8))) short v8s;
typedef __attribute__((ext_vector_type(4))) float v4f;

static __device__ __forceinline__ unsigned short f2bf(float f) {
  unsigned int u = __float_as_uint(f);
  u += 0x7fffu + ((u >> 16) & 1u);   // RNE
  return (unsigned short)(u >> 16);
}
static __device__ __forceinline__ float bf2f(unsigned short s) {
  return __uint_as_float(((unsigned int)s) << 16);
}
static __device__ __forceinline__ float bflo(unsigned int u) {
  return __uint_as_float(u << 16);
}
static __device__ __forceinline__ float bfhi(unsigned int u) {
  return __uint_as_float(u & 0xffff0000u);
}

// async global->LDS, 16B per lane; LDS dest is wave-uniform base + lane*16
static __device__ __forceinline__ void gload_lds16(const void* g, void* l) {
  __builtin_amdgcn_global_load_lds(
      (const __attribute__((address_space(1))) void*)g,
      (__attribute__((address_space(3))) void*)l, 16, 0, 0);
}

// dequant-accumulate 8 uint8 feats (uint2) scaled by s into a0..a7
#define ACC8(v, s)                                            \
  {                                                           \
    a0 += (s) * (float)((v).x & 0xffu);                       \
    a1 += (s) * (float)(((v).x >> 8) & 0xffu);                \
    a2 += (s) * (float)(((v).x >> 16) & 0xffu);               \
    a3 += (s) * (float)((v).x >> 24);                         \
    a4 += (s) * (float)((v).y & 0xffu);                       \
    a5 += (s) * (float)(((v).y >> 8) & 0xffu);                \
    a6 += (s) * (float)(((v).y >> 16) & 0xffu);               \
    a7 += (s) * (float)((v).y >> 24);                         \
  }

// ---------------- preprocessing ----------------
__global__ void k_degree(const int* __restrict__ dst, int* __restrict__ deg,
                         int* __restrict__ eord, int E) {
  int e = blockIdx.x * blockDim.x + threadIdx.x;
  if (e < E) eord[e] = atomicAdd(&deg[dst[e]], 1);
}

// single-dispatch exclusive scan (decoupled lookback, flag bit 31) + dinv.
__global__ void k_scan(const int* __restrict__ deg, int* __restrict__ scanbuf,
                       int* __restrict__ rowptr, float* __restrict__ dinv, int N) {
  __shared__ int s[256];
  __shared__ int sbase;
  int bid = blockIdx.x, tid = threadIdx.x;
  int base = bid * 1024 + tid * 4;
  int v[4]; int t = 0;
#pragma unroll
  for (int j = 0; j < 4; ++j) { int idx = base + j; v[j] = (idx < N) ? deg[idx] : 0; t += v[j]; }
  s[tid] = t; __syncthreads();
  for (int d = 1; d < 256; d <<= 1) {
    int u = (tid >= d) ? s[tid - d] : 0;
    __syncthreads();
    s[tid] += u;
    __syncthreads();
  }
  int myexcl = s[tid] - t;
  int blocktotal = s[255];
  if (tid == 0) atomicExch(&scanbuf[bid], blocktotal | 0x80000000);

  int pre = 0;
  for (int p = tid; p < bid; p += 256) {
    int val;
    do { val = atomicAdd(&scanbuf[p], 0); } while (!(val & 0x80000000));
    pre += val & 0x7fffffff;
  }
  __syncthreads();
  s[tid] = pre; __syncthreads();
  for (int d = 128; d > 0; d >>= 1) { if (tid < d) s[tid] += s[tid + d]; __syncthreads(); }
  if (tid == 0) sbase = s[0];
  __syncthreads();

  int run = sbase + myexcl;
#pragma unroll
  for (int j = 0; j < 4; ++j) {
    int idx = base + j;
    if (idx < N) {
      rowptr[idx] = run;
      dinv[idx] = rsqrtf((float)(1 + v[j]));
    }
    run += v[j];
    if (idx == N - 1) rowptr[N] = run;
  }
}

// fragment-major weight pack helper
static __device__ __forceinline__ void wtf_one(const float* __restrict__ W,
                                               unsigned short* __restrict__ WTF,
                                               int idx, int Kreal, int KK) {
  int j = idx & 7;
  int c = idx >> 3;
  int l15 = c & 15;
  int quad = (c >> 4) & 3;
  int kk = (c >> 6) % KK;
  int t = c / (64 * KK);
  int k = kk * 32 + quad * 8 + j;
  int n = t * 16 + l15;
  WTF[idx] = (k < Kreal) ? f2bf(W[k * 128 + n]) : (unsigned short)0;
}

// merged prep: atomic-free CSR scatter | xcast(8/thread) | wtf | bounds | out-zero
__global__ void k_prep(const int* __restrict__ src, const int* __restrict__ dst,
                       const int* __restrict__ rowptr, const int* __restrict__ eord,
                       int* __restrict__ col, int E,
                       const float* __restrict__ x, const float* __restrict__ dinv,
                       unsigned short* __restrict__ xb, int N,
                       const float* __restrict__ W1, const float* __restrict__ W2,
                       const float* __restrict__ W3,
                       unsigned short* __restrict__ W1F, unsigned short* __restrict__ W2F,
                       unsigned short* __restrict__ W3F,
                       const int* __restrict__ batch, int* __restrict__ gstart, int G,
                       float* __restrict__ out,
                       int SB, int XB, int WB, int BB) {
  int blk = blockIdx.x;
  if (blk < SB) {
    int e = blk * 256 + threadIdx.x;
    if (e < E) col[rowptr[dst[e]] + eord[e]] = src[e];
  } else if (blk < SB + XB) {
    int idx = (blk - SB) * 256 + threadIdx.x;
    if (idx < N * 4) {
      int n = idx >> 2, s4 = idx & 3, f0 = s4 * 8;
      float di = dinv[n];
      unsigned int w[4];
#pragma unroll
      for (int j = 0; j < 8; j += 2) {
        int f = f0 + j;
        float v0 = (f < DIN) ? x[(size_t)n * DIN + f] * di : 0.f;
        float v1 = (f + 1 < DIN) ? x[(size_t)n * DIN + f + 1] * di : 0.f;
        w[j >> 1] = (unsigned int)f2bf(v0) | ((unsigned int)f2bf(v1) << 16);
      }
      uint4 o; o.x = w[0]; o.y = w[1]; o.z = w[2]; o.w = w[3];
      ((uint4*)xb)[idx] = o;
    }
  } else if (blk < SB + XB + WB) {
    int idx = (blk - SB - XB) * 256 + threadIdx.x;
    if (idx < 4096) wtf_one(W1, W1F, idx, DIN, 1);
    else if (idx < 20480) wtf_one(W2, W2F, idx - 4096, 128, 4);
    else if (idx < 36864) wtf_one(W3, W3F, idx - 20480, 128, 4);
  } else if (blk < SB + XB + WB + BB) {
    int i = (blk - SB - XB - WB) * 256 + threadIdx.x;
    if (i >= N) return;
    int b = batch[i];
    int prev = (i == 0) ? -1 : batch[i - 1];
    for (int g = prev + 1; g <= b; ++g) gstart[g] = i;
    if (i == N - 1)
      for (int g = b + 1; g <= G; ++g) gstart[g] = N;
  } else {
    int idx = (blk - SB - XB - WB - BB) * 256 + threadIdx.x;
    if (idx < G * 32)
      ((float4*)out)[idx] = make_float4(0.f, 0.f, 0.f, 0.f);
  }
}

// ---------------- fused aggregate + MFMA GEMM (layers 1,2) ----------------
// 256 threads / 16 nodes / 4 waves; each wave owns 4 nodes end-to-end.
// K=32: input bf16 xb (64B rows). K=128: input uint8 rows (128B) + scale.
// Output: uint8 rows + per-row scale (next-layer dinv pre-folded).
template <int K>
__global__ __launch_bounds__(256, 7) void k_fused(const void* __restrict__ hin,
                                                  const float* __restrict__ hscale,
                                                  const unsigned short* __restrict__ WTF,
                                                  const float* __restrict__ b,
                                                  const int* __restrict__ rowptr,
                                                  const int* __restrict__ col,
                                                  const float* __restrict__ dinv,
                                                  unsigned char* __restrict__ Cq,
                                                  float* __restrict__ Cs, int N) {
  constexpr int KK = K / 32;
  constexpr int KP = (K == 128) ? 136 : 40;
  constexpr int CP = 132;
  constexpr int SMSZ = (16 * KP > 16 * CP) ? 16 * KP : 16 * CP;
  constexpr int WCAP = 32;                      // edges per wave per round
  constexpr int RB = (K == 128) ? 128 : 64;     // staged row bytes
  __shared__ __align__(16) unsigned short sm[SMSZ];
  __shared__ __align__(16) unsigned char stg[4 * WCAP * RB];
  __shared__ int scol[4 * WCAP];
  __shared__ float swsc[(K == 128) ? 4 * WCAP : 1];

  int tid = threadIdx.x;
  int l16 = tid & 15;
  int g = tid >> 4;                 // 16 groups; group g owns node row0+g
  int lane = tid & 63, wv = tid >> 6, quad = lane >> 4, l15 = lane & 15;
  int row0 = blockIdx.x * 16;
  int node = row0 + g;

  // ---- phase 1a: self term + ranges ----
  float a0 = 0.f, a1 = 0.f, a2 = 0.f, a3 = 0.f, a4 = 0.f, a5 = 0.f, a6 = 0.f, a7 = 0.f;
  int e0 = 0, e1 = 0; float di = 0.f;
  if (node < N) {
    e0 = rowptr[node]; e1 = rowptr[node + 1]; di = dinv[node];
    if constexpr (K == 32) {
      unsigned int u = ((const unsigned int*)hin)[(size_t)node * 16 + l16];
      a0 = bflo(u); a1 = bfhi(u);
    } else {
      uint2 u = ((const uint2*)hin)[(size_t)node * 16 + l16];
      float s = hscale[node];
      ACC8(u, s);
    }
  }
  // wave-local edge range (4 nodes per wave)
  int nb0 = row0 + wv * 4; if (nb0 > N) nb0 = N;
  int nb1 = nb0 + 4; if (nb1 > N - nb0 + nb0) nb1 = nb1;   // (kept simple below)
  nb1 = row0 + wv * 4 + 4; if (nb1 > N) nb1 = N;
  int web = rowptr[nb0];
  int wee = rowptr[nb1];

  // ---- phase 1b: wave-private stage + reduce (NO block barriers) ----
  for (int c0 = web; c0 < wee; c0 += WCAP) {
    if (lane < WCAP) {
      int e = c0 + lane;
      int c = (e < wee) ? col[e] : 0;          // clamp: safe row 0
      scol[wv * WCAP + lane] = c;
      if constexpr (K == 128) swsc[wv * WCAP + lane] = hscale[c];
    }
    if constexpr (K == 128) {
      // 32 slots x 8 lanes = 4 issues
#pragma unroll
      for (int q = 0; q < 4; ++q) {
        int slot = q * 8 + (lane >> 3);
        int row = scol[wv * WCAP + slot];
        const unsigned char* gp = (const unsigned char*)hin + (size_t)row * 128 + (lane & 7) * 16;
        gload_lds16(gp, &stg[(wv * WCAP + slot) * 128]);
      }
    } else {
      // 32 slots x 4 lanes = 2 issues
#pragma unroll
      for (int q = 0; q < 2; ++q) {
        int slot = q * 16 + (lane >> 2);
        int row = scol[wv * WCAP + slot];
        const unsigned short* gp = (const unsigned short*)hin + (size_t)row * 32 + (lane & 3) * 8;
        gload_lds16(gp, &stg[(wv * WCAP + slot) * 64]);
      }
    }
    // wave-local drain happens via compiler vmcnt before first stg read
    int lo = (e0 > c0) ? e0 : c0;
    int hi = (e1 < c0 + WCAP) ? e1 : (c0 + WCAP);
    int e2 = lo;
    for (; e2 + 2 <= hi; e2 += 2) {
      int i0 = wv * WCAP + (e2 - c0), i1 = i0 + 1;
      if constexpr (K == 32) {
        unsigned int w0 = *(const unsigned int*)&stg[i0 * 64 + l16 * 4];
        unsigned int w1 = *(const unsigned int*)&stg[i1 * 64 + l16 * 4];
        a0 += bflo(w0); a1 += bfhi(w0);
        a0 += bflo(w1); a1 += bfhi(w1);
      } else {
        uint2 w0 = *(const uint2*)&stg[i0 * 128 + l16 * 8];
        uint2 w1 = *(const uint2*)&stg[i1 * 128 + l16 * 8];
        float s0 = swsc[i0], s1 = swsc[i1];
        ACC8(w0, s0);
        ACC8(w1, s1);
      }
    }
    if (e2 < hi) {
      int i0 = wv * WCAP + (e2 - c0);
      if constexpr (K == 32) {
        unsigned int w0 = *(const unsigned int*)&stg[i0 * 64 + l16 * 4];
        a0 += bflo(w0); a1 += bfhi(w0);
      } else {
        uint2 w0 = *(const uint2*)&stg[i0 * 128 + l16 * 8];
        float s0 = swsc[i0];
        ACC8(w0, s0);
      }
    }
  }

  // ---- phase 1c: deposit normalized bf16 A-tile (own wave's rows) ----
  if constexpr (K == 32) {
    *(unsigned int*)&sm[g * KP + l16 * 2] =
        (unsigned int)f2bf(a0 * di) | ((unsigned int)f2bf(a1 * di) << 16);
  } else {
    uint4 o;
    o.x = (unsigned int)f2bf(a0 * di) | ((unsigned int)f2bf(a1 * di) << 16);
    o.y = (unsigned int)f2bf(a2 * di) | ((unsigned int)f2bf(a3 * di) << 16);
    o.z = (unsigned int)f2bf(a4 * di) | ((unsigned int)f2bf(a5 * di) << 16);
    o.w = (unsigned int)f2bf(a6 * di) | ((unsigned int)f2bf(a7 * di) << 16);
    *(uint4*)&sm[g * KP + l16 * 8] = o;
  }
  __syncthreads();                  // the ONE pre-MFMA rendezvous

  // ---- phase 2: A-frags from LDS; 4 waves = 4 t-pairs on one 16-row tile ----
  v8s af[KK];
#pragma unroll
  for (int kk = 0; kk < KK; ++kk)
    af[kk] = *(const v8s*)&sm[l15 * KP + kk * 32 + quad * 8];
  __syncthreads();

  // hoisted next-layer pre-scale: dinv for this lane's 4 output rows
  int crow0 = row0 + quad * 4;
  float dr[4];
  if (crow0 + 3 < N) {
    float4 d4 = *(const float4*)&dinv[crow0];
    dr[0] = d4.x; dr[1] = d4.y; dr[2] = d4.z; dr[3] = d4.w;
  } else {
#pragma unroll
    for (int i = 0; i < 4; ++i) dr[i] = (crow0 + i < N) ? dinv[crow0 + i] : 0.f;
  }

#pragma unroll
  for (int tt = 0; tt < 2; ++tt) {
    int t = wv * 2 + tt;
    v4f acc = {0.f, 0.f, 0.f, 0.f};
#pragma unroll
    for (int kk = 0; kk < KK; ++kk) {
      v8s bf = *(const v8s*)(WTF + (size_t)(((t * KK + kk) * 4 + quad) * 16 + l15) * 8);
      acc = __builtin_amdgcn_mfma_f32_16x16x32_bf16(af[kk], bf, acc, 0, 0, 0);
    }
    float bias = b[t * 16 + l15];
#pragma unroll
    for (int i = 0; i < 4; ++i) {
      float o = fmaxf(acc[i] + bias, 0.f) * dr[i];
      sm[(quad * 4 + i) * CP + t * 16 + l15] = f2bf(o);
    }
  }
  __syncthreads();

  // ---- phase 3: per-row uint8 quantize + coalesced store ----
  {
    uint4 u = *(const uint4*)&sm[g * CP + l16 * 8];
    float f0 = bflo(u.x), f1 = bfhi(u.x), f2 = bflo(u.y), f3 = bfhi(u.y);
    float f4 = bflo(u.z), f5 = bfhi(u.z), f6 = bflo(u.w), f7 = bfhi(u.w);
    float m = fmaxf(fmaxf(fmaxf(f0, f1), fmaxf(f2, f3)),
                    fmaxf(fmaxf(f4, f5), fmaxf(f6, f7)));
    m = fmaxf(m, __shfl_xor(m, 1));
    m = fmaxf(m, __shfl_xor(m, 2));
    m = fmaxf(m, __shfl_xor(m, 4));
    m = fmaxf(m, __shfl_xor(m, 8));
    float inv = (m > 0.f) ? 255.f / m : 0.f;
    unsigned q0 = (unsigned)__float2int_rn(fminf(f0 * inv, 255.f));
    unsigned q1 = (unsigned)__float2int_rn(fminf(f1 * inv, 255.f));
    unsigned q2 = (unsigned)__float2int_rn(fminf(f2 * inv, 255.f));
    unsigned q3 = (unsigned)__float2int_rn(fminf(f3 * inv, 255.f));
    unsigned q4 = (unsigned)__float2int_rn(fminf(f4 * inv, 255.f));
    unsigned q5 = (unsigned)__float2int_rn(fminf(f5 * inv, 255.f));
    unsigned q6 = (unsigned)__float2int_rn(fminf(f6 * inv, 255.f));
    unsigned q7 = (unsigned)__float2int_rn(fminf(f7 * inv, 255.f));
    uint2 o;
    o.x = q0 | (q1 << 8) | (q2 << 16) | (q3 << 24);
    o.y = q4 | (q5 << 8) | (q6 << 16) | (q7 << 24);
    int row = row0 + g;
    if (row < N) {
      ((uint2*)Cq)[(size_t)row * 16 + l16] = o;
      if (l16 == 0) Cs[row] = m * (1.f / 255.f);
    }
  }
}

// ---------------- layer 3: fused aggregate + GEMM + pool-atomics ----------------
__global__ __launch_bounds__(256, 7) void k_fused_pool(const unsigned char* __restrict__ hin,
                                                       const float* __restrict__ hscale,
                                                       const unsigned short* __restrict__ WTF,
                                                       const float* __restrict__ b,
                                                       const int* __restrict__ rowptr,
                                                       const int* __restrict__ col,
                                                       const float* __restrict__ dinv,
                                                       const int* __restrict__ batch,
                                                       float* __restrict__ out, int N) {
  constexpr int KK = 4, KP = 136, CP = 132;
  constexpr int SMSZ = 16 * KP;
  constexpr int WCAP = 32;
  __shared__ __align__(16) unsigned short sm[SMSZ];
  __shared__ __align__(16) unsigned char stg[4 * WCAP * 128];
  __shared__ int scol[4 * WCAP];
  __shared__ float swsc[4 * WCAP];
  __shared__ int sbatch[16];

  int tid = threadIdx.x;
  int l16 = tid & 15;
  int g = tid >> 4;
  int lane = tid & 63, wv = tid >> 6, quad = lane >> 4, l15 = lane & 15;
  int row0 = blockIdx.x * 16;
  int node = row0 + g;

  if (tid < 16) sbatch[tid] = (row0 + tid < N) ? batch[row0 + tid] : -1;

  // ---- phase 1a ----
  float a0 = 0.f, a1 = 0.f, a2 = 0.f, a3 = 0.f, a4 = 0.f, a5 = 0.f, a6 = 0.f, a7 = 0.f;
  int e0 = 0, e1 = 0; float di = 0.f;
  if (node < N) {
    e0 = rowptr[node]; e1 = rowptr[node + 1]; di = dinv[node];
    uint2 u = ((const uint2*)hin)[(size_t)node * 16 + l16];
    float s = hscale[node];
    ACC8(u, s);
  }
  int nb0 = row0 + wv * 4; if (nb0 > N) nb0 = N;
  int nb1 = row0 + wv * 4 + 4; if (nb1 > N) nb1 = N;
  int web = rowptr[nb0];
  int wee = rowptr[nb1];

  // ---- phase 1b: wave-private stage + reduce ----
  for (int c0 = web; c0 < wee; c0 += WCAP) {
    if (lane < WCAP) {
      int e = c0 + lane;
      int c = (e < wee) ? col[e] : 0;
      scol[wv * WCAP + lane] = c;
      swsc[wv * WCAP + lane] = hscale[c];
    }
#pragma unroll
    for (int q = 0; q < 4; ++q) {
      int slot = q * 8 + (lane >> 3);
      int row = scol[wv * WCAP + slot];
      const unsigned char* gp = hin + (size_t)row * 128 + (lane & 7) * 16;
      gload_lds16(gp, &stg[(wv * WCAP + slot) * 128]);
    }
    int lo = (e0 > c0) ? e0 : c0;
    int hi = (e1 < c0 + WCAP) ? e1 : (c0 + WCAP);
    int e2 = lo;
    for (; e2 + 2 <= hi; e2 += 2) {
      int i0 = wv * WCAP + (e2 - c0), i1 = i0 + 1;
      uint2 w0 = *(const uint2*)&stg[i0 * 128 + l16 * 8];
      uint2 w1 = *(const uint2*)&stg[i1 * 128 + l16 * 8];
      float s0 = swsc[i0], s1 = swsc[i1];
      ACC8(w0, s0);
      ACC8(w1, s1);
    }
    if (e2 < hi) {
      int i0 = wv * WCAP + (e2 - c0);
      uint2 w0 = *(const uint2*)&stg[i0 * 128 + l16 * 8];
      float s0 = swsc[i0];
      ACC8(w0, s0);
    }
  }

  // ---- phase 1c: deposit normalized bf16 A-tile ----
  {
    uint4 o;
    o.x = (unsigned int)f2bf(a0 * di) | ((unsigned int)f2bf(a1 * di) << 16);
    o.y = (unsigned int)f2bf(a2 * di) | ((unsigned int)f2bf(a3 * di) << 16);
    o.z = (unsigned int)f2bf(a4 * di) | ((unsigned int)f2bf(a5 * di) << 16);
    o.w = (unsigned int)f2bf(a6 * di) | ((unsigned int)f2bf(a7 * di) << 16);
    *(uint4*)&sm[g * KP + l16 * 8] = o;
  }
  __syncthreads();

  // ---- phase 2 (no epilogue scaling: pool needs raw h3) ----
  v8s af[KK];
#pragma unroll
  for (int kk = 0; kk < KK; ++kk)
    af[kk] = *(const v8s*)&sm[l15 * KP + kk * 32 + quad * 8];
  __syncthreads();

#pragma unroll
  for (int tt = 0; tt < 2; ++tt) {
    int t = wv * 2 + tt;
    v4f acc = {0.f, 0.f, 0.f, 0.f};
#pragma unroll
    for (int kk = 0; kk < KK; ++kk) {
      v8s bf = *(const v8s*)(WTF + (size_t)(((t * KK + kk) * 4 + quad) * 16 + l15) * 8);
      acc = __builtin_amdgcn_mfma_f32_16x16x32_bf16(af[kk], bf, acc, 0, 0, 0);
    }
    float bias = b[t * 16 + l15];
#pragma unroll
    for (int i = 0; i < 4; ++i) {
      float o = fmaxf(acc[i] + bias, 0.f);
      sm[(quad * 4 + i) * CP + t * 16 + l15] = f2bf(o);
    }
  }
  __syncthreads();

  // ---- phase 3: segment-sum the 16 sorted rows, atomicAdd partials ----
  int f = tid & 127;
  int grp = tid >> 7;               // 2 groups x 8 rows
  float run = 0.f;
  int cur = -1;
#pragma unroll
  for (int j = 0; j < 8; ++j) {
    int r = grp * 8 + j;
    int gg = sbatch[r];
    if (gg != cur) {
      if (cur >= 0) atomicAdd(&out[(size_t)cur * 128 + f], run);
      run = 0.f; cur = gg;
    }
    if (gg >= 0) run += bf2f(sm[r * CP + f]);
  }
  if (cur >= 0) atomicAdd(&out[(size_t)cur * 128 + f], run);
}

// divide pooled sums by segment counts
__global__ void k_finalize(float* __restrict__ out, const int* __restrict__ gstart, int G) {
  int idx = blockIdx.x * blockDim.x + threadIdx.x;
  if (idx >= G * 128) return;
  int g = idx >> 7;
  float cnt = (float)(gstart[g + 1] - gstart[g]);
  out[idx] = out[idx] / fmaxf(cnt, 1.f);
}

extern "C" void kernel_launch(void* const* d_in, const int* in_sizes, int n_in,
                              void* d_out, int out_size, void* d_ws, size_t ws_size,
                              hipStream_t stream) {
  const float* x  = (const float*)d_in[0];
  const int* ei   = (const int*)d_in[1];
  const int* batch = (const int*)d_in[2];
  const float* W1 = (const float*)d_in[3];
  const float* b1 = (const float*)d_in[4];
  const float* W2 = (const float*)d_in[5];
  const float* b2 = (const float*)d_in[6];
  const float* W3 = (const float*)d_in[7];
  const float* b3 = (const float*)d_in[8];
  float* out = (float*)d_out;
  int N = in_sizes[2];
  int E = in_sizes[1] / 2;
  int G = out_size / HD;
  const int* src = ei;
  const int* dst = ei + E;

  size_t off = 0;
  char* ws = (char*)d_ws;
  auto alloc = [&](size_t bytes) -> void* {
    void* p = ws + off;
    off += (bytes + 255) & ~(size_t)255;
    return p;
  };
  int nb1024 = (N + 1023) / 1024;
  int*   deg     = (int*)alloc((size_t)N * 4);
  int*   scanbuf = (int*)alloc((size_t)nb1024 * 4);   // contiguous after deg -> one memset
  float* dinv    = (float*)alloc((size_t)N * 4);
  int*   rowptr  = (int*)alloc((size_t)(N + 1) * 4);
  int*   eord    = (int*)alloc((size_t)E * 4);
  int*   col     = (int*)alloc((size_t)E * 4);
  int*   gstart  = (int*)alloc((size_t)(G + 1) * 4);
  unsigned short* xb  = (unsigned short*)alloc((size_t)N * 32 * 2);
  unsigned char*  hAq = (unsigned char*)alloc((size_t)N * 128);
  float*          hAs = (float*)alloc((size_t)N * 4);
  unsigned char*  hBq = (unsigned char*)alloc((size_t)N * 128);
  float*          hBs = (float*)alloc((size_t)N * 4);
  unsigned short* W1F = (unsigned short*)alloc(4096 * 2);
  unsigned short* W2F = (unsigned short*)alloc(16384 * 2);
  unsigned short* W3F = (unsigned short*)alloc(16384 * 2);
  (void)ws_size; (void)n_in;

  size_t zbytes = (size_t)((char*)dinv - (char*)deg);  // deg + scanbuf region
  hipMemsetAsync(deg, 0, zbytes, stream);
  k_degree<<<(E + 255) / 256, 256, 0, stream>>>(dst, deg, eord, E);
  k_scan<<<nb1024, 256, 0, stream>>>(deg, scanbuf, rowptr, dinv, N);

  int SB = (E + 255) / 256;
  int XB = (N * 4 + 255) / 256;
  int WB = 144;
  int BB = (N + 255) / 256;
  int ZB = (G * 32 + 255) / 256;   // out zero, float4/thread
  k_prep<<<SB + XB + WB + BB + ZB, 256, 0, stream>>>(src, dst, rowptr, eord, col, E,
                                                     x, dinv, xb, N,
                                                     W1, W2, W3, W1F, W2F, W3F,
                                                     batch, gstart, G, out,
                                                     SB, XB, WB, BB);

  int fusedBlocks = (N + 15) / 16;
  k_fused<32><<<fusedBlocks, 256, 0, stream>>>(xb, nullptr, W1F, b1, rowptr, col, dinv,
                                               hAq, hAs, N);
  k_fused<128><<<fusedBlocks, 256, 0, stream>>>(hAq, hAs, W2F, b2, rowptr, col, dinv,
                                                hBq, hBs, N);
  k_fused_pool<<<fusedBlocks, 256, 0, stream>>>(hBq, hBs, W3F, b3, rowptr, col, dinv,
                                                batch, out, N);
  k_finalize<<<(G * 128 + 255) / 256, 256, 0, stream>>>(out, gstart, G);
}